// Round 11
// baseline (495.001 us; speedup 1.0000x reference)
//
#include <hip/hip_runtime.h>
#include <stdint.h>
#include <math.h>

#define N_ANCH   1000000
#define N4       (N_ANCH / 4)          // 250000 uint4 key packs
#define NBLK256  ((N4 + 255) / 256)    // 977 blocks (uint4 kernels)
#define SBLK     977                   // k_score grid (grid-stride, ~4 iters/thread)
#define PRE_K    6000
#define POST_K   1000
#define WORDS    94            // ceil(6000/64) -> 6016 bit columns
#define ROWS     6016          // WORDS*64
#define W_IMG    1333.0f
#define H_IMG    800.0f

#define NS       7168          // candidate capacity (112 blocks of 64)
#define RBLK     112           // rank blocks

#define OLDK     16            // k_nms old-kept gather batch: 16*64 >= 999+63 rows

// ws layout (bytes). NOTE: the 16-bit histogram (256 KiB) is ALIASED onto the
// first 256 KiB of the mask buffer — hist is dead after k_cut16, and k_iou
// (which writes mask) runs strictly later in the stream.
#define OFF_KEYS   0x000000u   // u32[1e6] = 4 MiB
#define OFF_CTRL   0x410000u   // [0]=count [1]=T16
#define OFF_CAND   0x410100u   // u64[NS] 56 KiB
#define OFF_BOXES  0x41F000u   // float4[6016]
#define OFF_VALID  0x437000u   // u32[6016]
#define OFF_MASK   0x440000u   // u64[6016*94]; first 256KiB doubles as hist16
#define OFF_HIST   OFF_MASK    // u32[65536]

__device__ __forceinline__ float ref_exp(float v) {
  return (float)exp((double)v);   // correctly-rounded f32 exp via double
}

__device__ __forceinline__ void decode_box(float ax, float ay, float az, float aw,
                                           float dx, float dy, float dz, float dw,
                                           float& x1, float& y1, float& x2, float& y2,
                                           bool& valid) {
  // bit-exact replica of reference fp32 op order (no FMA contraction)
  float wa = __fsub_rn(az, ax);
  float ha = __fsub_rn(aw, ay);
  float xa = __fadd_rn(ax, __fmul_rn(0.5f, wa));
  float ya = __fadd_rn(ay, __fmul_rn(0.5f, ha));
  float x  = __fadd_rn(__fmul_rn(dx, wa), xa);
  float y  = __fadd_rn(__fmul_rn(dy, ha), ya);
  float w  = __fmul_rn(ref_exp(dz), wa);
  float h  = __fmul_rn(ref_exp(dw), ha);
  float hw = __fmul_rn(0.5f, w);
  float hh = __fmul_rn(0.5f, h);
  x1 = fminf(fmaxf(__fsub_rn(x, hw), 0.0f), W_IMG - 1.0f);
  y1 = fminf(fmaxf(__fsub_rn(y, hh), 0.0f), H_IMG - 1.0f);
  x2 = fminf(fmaxf(__fadd_rn(x, hw), 0.0f), W_IMG - 1.0f);
  y2 = fminf(fmaxf(__fadd_rn(y, hh), 0.0f), H_IMG - 1.0f);
  valid = (__fsub_rn(x2, x1) >= 16.0f) && (__fsub_rn(y2, y1) >= 16.0f);
}

// wave-uniform 64-bit broadcast via v_readlane
__device__ __forceinline__ uint64_t bcast64(uint64_t v, int lane) {
  uint32_t lo = (uint32_t)__builtin_amdgcn_readlane((int)(uint32_t)v, lane);
  uint32_t hi = (uint32_t)__builtin_amdgcn_readlane((int)(uint32_t)(v >> 32), lane);
  return ((uint64_t)hi << 32) | lo;
}

__device__ __forceinline__ uint64_t shflxor64(uint64_t v, int m) {
  uint32_t lo = (uint32_t)__shfl_xor((int)(uint32_t)v, m, 64);
  uint32_t hi = (uint32_t)__shfl_xor((int)(uint32_t)(v >> 32), m, 64);
  return ((uint64_t)hi << 32) | lo;
}

// ---- K0: fused decode + logit-bit key + 16-bit GLOBAL histogram ----
// Grid-stride (977 blocks, ~4 anchors/thread, coalesced). 16-bit bins make a
// single cut sufficient (cut bin holds ~270 keys << NS-PRE_K margin), deleting
// the old histA/hist2/cut2 kernels and two full 4MB key re-reads.
// Valid-key atomics are scattered (worst bin ~2K); invalid bin wave-aggregated.
__global__ void __launch_bounds__(256) k_score(const float4* __restrict__ anchors,
                                               const float4* __restrict__ deltas,
                                               const float*  __restrict__ logits,
                                               uint32_t* __restrict__ keys,
                                               uint32_t* __restrict__ hist) {
  int tid = threadIdx.x, lane = tid & 63;
  for (int i = blockIdx.x * 256 + tid; i < N_ANCH; i += SBLK * 256) {
    float4 a = anchors[i];
    float4 d = deltas[i];
    // fast f32 decode (filter only; exact op order irrelevant under margin)
    float wa = a.z - a.x, ha = a.w - a.y;
    float xa = a.x + 0.5f * wa, ya = a.y + 0.5f * ha;
    float x = d.x * wa + xa, y = d.y * ha + ya;
    float w = __expf(d.z) * wa, h = __expf(d.w) * ha;
    float fx1 = fminf(fmaxf(x - 0.5f * w, 0.0f), W_IMG - 1.0f);
    float fx2 = fminf(fmaxf(x + 0.5f * w, 0.0f), W_IMG - 1.0f);
    float fy1 = fminf(fmaxf(y - 0.5f * h, 0.0f), H_IMG - 1.0f);
    float fy2 = fminf(fmaxf(y + 0.5f * h, 0.0f), H_IMG - 1.0f);
    float X = fx2 - fx1, Y = fy2 - fy1;
    bool valid = (X >= 16.0f) && (Y >= 16.0f);
    if (fabsf(X - 16.0f) < 0.02f || fabsf(Y - 16.0f) < 0.02f) {
      float ex1, ey1, ex2, ey2; bool vv;      // borderline: exact f64 recheck (rare)
      decode_box(a.x, a.y, a.z, a.w, d.x, d.y, d.z, d.w, ex1, ey1, ex2, ey2, vv);
      valid = vv;
    }
    uint32_t u = __float_as_uint(logits[i]);
    uint32_t o = (u & 0x80000000u) ? ~u : (u | 0x80000000u);  // ascending in logit
    uint32_t kd = valid ? ~o : 0xFFFFFFFFu;                   // ascending key = descending logit
    keys[i] = kd;
    uint64_t invb = __ballot(!valid);
    if (valid) {
      atomicAdd(&hist[kd >> 16], 1u);
    } else if ((invb & ((1ull << lane) - 1ull)) == 0ull) {
      atomicAdd(&hist[0xFFFFu], (uint32_t)__popcll((unsigned long long)invb));
    }
  }
}

// ---- K1: single cut over 64K bins, ONE block. Writes ctrl[1]=T16.
// Kernel boundary publishes ctrl (no fences). Thread t owns bins [64t, 64t+64).
__global__ void __launch_bounds__(1024) k_cut16(const uint32_t* __restrict__ hist,
                                                uint32_t* __restrict__ ctrl) {
  __shared__ uint32_t part[1024];
  int t = threadIdx.x;
  const uint4* h4 = (const uint4*)hist;
  uint32_t tot = 0;
  #pragma unroll
  for (int k = 0; k < 16; k++) {
    uint4 q = h4[t * 16 + k];
    tot += q.x + q.y + q.z + q.w;
  }
  part[t] = tot;
  __syncthreads();
  uint32_t inc = tot;
  for (int off = 1; off < 1024; off <<= 1) {
    uint32_t u = (t >= off) ? part[t - off] : 0u;
    __syncthreads();
    inc += u;
    part[t] = inc;
    __syncthreads();
  }
  uint32_t ex = inc - tot;
  if (ex < PRE_K && inc >= PRE_K) {      // exactly one thread wins (total >= PRE_K always)
    uint32_t run = ex;
    bool done = false;
    for (int k = 0; k < 16 && !done; k++) {
      uint4 q = h4[t * 16 + k];
      uint32_t b[4] = { q.x, q.y, q.z, q.w };
      for (int e = 0; e < 4; e++) {
        if (run + b[e] >= PRE_K) { ctrl[1] = (uint32_t)(64 * t + 4 * k + e); done = true; break; }
        run += b[e];
      }
    }
  }
}

// ---- K2: compact candidates (key prefix <= T16) + exact-sigmoid re-key ----
// Block-aggregated: ONE global atomic per block. cand order nondeterministic;
// fine, k_rank ranks by VALUE. ctrl passed non-restrict (cnt aliases ctrl[0]).
__global__ void __launch_bounds__(256) k_compact(const uint4* __restrict__ keys4,
                                                 const float* __restrict__ logits,
                                                 uint32_t* ctrl,
                                                 uint64_t* __restrict__ cand) {
  __shared__ uint32_t wcnt[4];
  __shared__ uint32_t bbase_s;
  int tid = threadIdx.x, lane = tid & 63, wv = tid >> 6;
  uint32_t T = ctrl[1];
  int i4 = blockIdx.x * 256 + tid;
  uint4 kk = make_uint4(~0u, ~0u, ~0u, ~0u);
  if (i4 < N4) kk = keys4[i4];
  uint32_t ks[4] = { kk.x, kk.y, kk.z, kk.w };
  bool pass[4]; uint64_t m[4];
  uint32_t tot = 0;
  #pragma unroll
  for (int e = 0; e < 4; e++) {
    pass[e] = (i4 < N4) && ((ks[e] >> 16) <= T);
    m[e] = __ballot(pass[e]);
    tot += (uint32_t)__popcll((unsigned long long)m[e]);
  }
  if (lane == 0) wcnt[wv] = tot;
  __syncthreads();
  if (tid == 0) {
    uint32_t bt = wcnt[0] + wcnt[1] + wcnt[2] + wcnt[3];
    bbase_s = bt ? atomicAdd(&ctrl[0], bt) : 0u;
  }
  __syncthreads();
  uint32_t wb = bbase_s;
  for (int w2 = 0; w2 < wv; w2++) wb += wcnt[w2];      // wave offset in block
  uint64_t lmask = (1ull << lane) - 1ull;
  #pragma unroll
  for (int e = 0; e < 4; e++) {
    if (pass[e]) {
      int i = 4 * i4 + e;
      uint32_t skey;
      if (ks[e] == 0xFFFFFFFFu) {
        skey = 0xFF800000u;                       // invalid -> -inf key
      } else {
        double xd = (double)logits[i];
        float s = (float)(1.0 / (1.0 + exp(-xd)));
        skey = 0x7FFFFFFFu & ~__float_as_uint(s); // descending-score -> ascending key
      }
      uint32_t p = wb + (uint32_t)__popcll((unsigned long long)(m[e] & lmask));
      if (p < NS) cand[p] = ((uint64_t)skey << 20) | (uint32_t)i;  // 52-bit packed
    }
    wb += (uint32_t)__popcll((unsigned long long)m[e]);
  }
}

// ---- K3: rank-by-count + gather/decode ----
// key64 all DISTINCT (idx embedded) -> rank is a bijection onto [0,M) equal to
// reference order (score desc, idx asc). 112 blocks x 4 waves.
__global__ void __launch_bounds__(256) k_rank(
    const uint32_t* __restrict__ ctrl,
    const uint64_t* __restrict__ cand,
    const float4* __restrict__ anchors,
    const float4* __restrict__ deltas,
    float4* __restrict__ boxes,
    uint32_t* __restrict__ valid) {
  __shared__ uint32_t part[4][64];
  int tid = threadIdx.x;
  int wv = tid >> 6, lane = tid & 63;
  int i = blockIdx.x * 64 + lane;            // own candidate slot (same for all 4 waves)
  uint32_t M = ctrl[0]; if (M > NS) M = NS;
  uint64_t myk = (i < (int)M) ? cand[i] : ~0ull;
  uint32_t cnt = 0;
  const int QUART = NS / 4;                  // 1792
  int jbase = wv * QUART;
  for (int s = 0; s < QUART / 64; s++) {     // 28 coalesced strips
    int j = jbase + s * 64 + lane;
    uint64_t c = (j < (int)M) ? cand[j] : ~0ull;   // sentinel: contributes 0
    #pragma unroll
    for (int s2 = 0; s2 < 64; s2++) {
      uint64_t kb = bcast64(c, s2);
      cnt += (kb < myk) ? 1u : 0u;
    }
  }
  part[wv][lane] = cnt;
  __syncthreads();
  if (wv != 0) return;
  uint32_t rank = part[0][lane] + part[1][lane] + part[2][lane] + part[3][lane];
  if (i < (int)M && rank < PRE_K) {
    uint32_t skey = (uint32_t)(myk >> 20);
    uint32_t idx  = (uint32_t)(myk & 0xFFFFFu);
    if (skey >= 0xFF800000u) {               // invalid candidate (take-everything case)
      boxes[rank] = make_float4(0.f, 0.f, 0.f, 0.f);
      valid[rank] = 0u;
    } else {
      float4 a = anchors[idx];
      float4 d = deltas[idx];
      float x1, y1, x2, y2; bool vv;
      decode_box(a.x, a.y, a.z, a.w, d.x, d.y, d.z, d.w, x1, y1, x2, y2, vv);
      boxes[rank] = make_float4(x1, y1, x2, y2);
      valid[rank] = 1u;
    }
  }
  // zero-fill all slots never touched by a rank-writer (bijection => no race)
  if ((i >= (int)M || i >= PRE_K) && i < ROWS) {
    boxes[i] = make_float4(0.f, 0.f, 0.f, 0.f);
    valid[i] = 0u;
  }
}

// ---- K4: IoU bitmask matrix, row-major mask[row*WORDS + w] ----
__global__ void __launch_bounds__(64) k_iou(const float4* __restrict__ boxes,
                                            uint64_t* __restrict__ mask) {
  int by = blockIdx.y, bx = blockIdx.x;
  if (bx < by) return;               // only words w >= row's group are ever read
  __shared__ float4 cb[64];
  int t = threadIdx.x;
  cb[t] = boxes[bx * 64 + t];
  __syncthreads();
  int i = by * 64 + t;
  float4 b = boxes[i];
  float ax1 = b.x, ay1 = b.y, ax2 = b.z, ay2 = b.w;
  float areaA = __fmul_rn(__fsub_rn(ax2, ax1), __fsub_rn(ay2, ay1));
  uint64_t bits = 0;
  for (int c = 0; c < 64; c++) {
    float4 o = cb[c];
    float areaB = __fmul_rn(__fsub_rn(o.z, o.x), __fsub_rn(o.w, o.y));
    float ix1 = fmaxf(ax1, o.x), iy1 = fmaxf(ay1, o.y);
    float ix2 = fminf(ax2, o.z), iy2 = fminf(ay2, o.w);
    float iw = fmaxf(__fsub_rn(ix2, ix1), 0.0f);
    float ih = fmaxf(__fsub_rn(iy2, iy1), 0.0f);
    float inter = __fmul_rn(iw, ih);
    float uni = __fsub_rn(__fadd_rn(areaA, areaB), inter);
    bool sup = (uni > 0.0f) && (__fdiv_rn(inter, uni) > 0.7f);
    bits |= ((uint64_t)sup) << c;
  }
  mask[(size_t)i * WORDS + bx] = bits;
}

// ---- K5: sequential NMS scan — single wave, LAZY column gather (unchanged, anchor) ----
__global__ void __launch_bounds__(64, 1) k_nms(const uint64_t* __restrict__ mask,
                                               const float4* __restrict__ boxes,
                                               const uint32_t* __restrict__ valid,
                                               float* __restrict__ out) {
  __shared__ uint32_t list[1088];     // kept rows in scan order (cnt < 1064)
  int lane = threadIdx.x;
  uint64_t lmask = (1ull << lane) - 1ull;
  int cnt = 0;
  uint64_t colv = mask[(size_t)lane * WORDS + 0];   // group-0 diagonal
  uint32_t vf = valid[lane];
  uint64_t cur = 0;                                 // removed[0] = 0
  for (int g = 0; g < WORDS; g++) {
    int base = g * 64;
    bool haveNext = (g + 1 < WORDS);
    // ---- issue gathers for removed[g+1] + next diag/valid (hidden under chain) ----
    uint64_t newv = 0, colv_n = 0, oldv[OLDK];
    uint32_t vf_n = 0, om = 0;
    if (haveNext) {
      newv   = mask[(size_t)(base + lane) * WORDS + (g + 1)];        // own row's col g+1
      colv_n = mask[(size_t)(base + 64 + lane) * WORDS + (g + 1)];   // next diag
      vf_n   = valid[base + 64 + lane];
      #pragma unroll
      for (int k = 0; k < OLDK; k++) {            // previously-kept rows' col g+1
        int t = 64 * k + lane;
        uint32_t row = (t < cnt) ? list[t] : 0u;  // clamped safe address
        om |= (t < cnt) ? (1u << k) : 0u;
        oldv[k] = mask[(size_t)row * WORDS + (g + 1)];
      }
    }
    // ---- branch-free 64-step decision chain (wave-uniform SALU) ----
    uint64_t vmask = __ballot(vf != 0u);
    uint64_t alive = vmask & ~cur;
    uint64_t kept = 0;
    #pragma unroll
    for (int r = 0; r < 64; r++) {
      uint64_t mr = bcast64(colv, r);
      uint64_t take = (alive >> r) & 1ull;
      kept |= take << r;
      alive &= ~(take ? mr : 0ull);
    }
    // ---- record kept rows (in-wave, no barrier) ----
    uint32_t below = (uint32_t)__popcll((unsigned long long)(kept & lmask));
    if ((kept >> lane) & 1ull) {
      uint32_t pos = (uint32_t)cnt + below;
      if (pos < 1088u) list[pos] = (uint32_t)(base + lane);
    }
    cnt += (int)__popcll((unsigned long long)kept);
    if (cnt >= POST_K || !haveNext) break;
    // ---- pin gather batch in VGPRs (defeat load sinking), then select-OR ----
    asm volatile("" : "+v"(newv),
                      "+v"(oldv[0]),  "+v"(oldv[1]),  "+v"(oldv[2]),  "+v"(oldv[3]),
                      "+v"(oldv[4]),  "+v"(oldv[5]),  "+v"(oldv[6]),  "+v"(oldv[7]),
                      "+v"(oldv[8]),  "+v"(oldv[9]),  "+v"(oldv[10]), "+v"(oldv[11]),
                      "+v"(oldv[12]), "+v"(oldv[13]), "+v"(oldv[14]), "+v"(oldv[15]));
    uint64_t acc = ((kept >> lane) & 1ull) ? newv : 0ull;
    #pragma unroll
    for (int k = 0; k < OLDK; k++)
      acc |= oldv[k] & (0ull - (uint64_t)((om >> k) & 1u));
    #pragma unroll
    for (int off = 1; off < 64; off <<= 1)        // wave-OR reduce
      acc |= shflxor64(acc, off);
    cur = bcast64(acc, 0);                        // wave-uniform removed[g+1]
    colv = colv_n; vf = vf_n;
  }
  __syncthreads();
  float4* outv = (float4*)out;
  for (int k = lane; k < POST_K; k += 64)
    outv[k] = (k < cnt) ? boxes[list[k]] : make_float4(0.f, 0.f, 0.f, 0.f);
}

extern "C" void kernel_launch(void* const* d_in, const int* in_sizes, int n_in,
                              void* d_out, int out_size, void* d_ws, size_t ws_size,
                              hipStream_t stream) {
  const float4* anchors = (const float4*)d_in[1];
  const float4* deltas  = (const float4*)d_in[2];
  const float*  logits  = (const float*)d_in[3];
  char* w = (char*)d_ws;
  uint32_t* keys  = (uint32_t*)(w + OFF_KEYS);
  uint32_t* hist  = (uint32_t*)(w + OFF_HIST);   // aliases mask[0..256KiB)
  uint32_t* ctrl  = (uint32_t*)(w + OFF_CTRL);
  uint64_t* cand  = (uint64_t*)(w + OFF_CAND);
  float4*   boxes = (float4*)(w + OFF_BOXES);
  uint32_t* valid = (uint32_t*)(w + OFF_VALID);
  uint64_t* mask  = (uint64_t*)(w + OFF_MASK);
  float*    out   = (float*)d_out;

  hipMemsetAsync(w + OFF_HIST, 0, 0x40000, stream);  // 64K-bin hist
  hipMemsetAsync(w + OFF_CTRL, 0, 256, stream);      // counters

  k_score<<<SBLK, 256, 0, stream>>>(anchors, deltas, logits, keys, hist);
  k_cut16<<<1, 1024, 0, stream>>>(hist, ctrl);
  k_compact<<<NBLK256, 256, 0, stream>>>((const uint4*)keys, logits, ctrl, cand);
  k_rank<<<RBLK, 256, 0, stream>>>(ctrl, cand, anchors, deltas, boxes, valid);
  k_iou<<<dim3(WORDS, WORDS), 64, 0, stream>>>(boxes, mask);
  k_nms<<<1, 64, 0, stream>>>(mask, boxes, valid, out);
}

// Round 12
// 264.829 us; speedup vs baseline: 1.8691x; 1.8691x over previous
//
#include <hip/hip_runtime.h>
#include <stdint.h>
#include <math.h>

#define N_ANCH   1000000
#define N4       (N_ANCH / 4)          // 250000 uint4 key packs
#define NBLK256  ((N4 + 255) / 256)    // 977 blocks (uint4 kernels)
#define PRE_K    6000
#define POST_K   1000
#define WORDS    94            // ceil(6000/64) -> 6016 bit columns
#define ROWS     6016          // WORDS*64
#define W_IMG    1333.0f
#define H_IMG    800.0f

#define HB       128           // k_score blocks (each flushes one 16K-bin partial)
#define NBIN     16384         // 14-bit histogram
#define NS       8192          // candidate capacity (M <= ~7300 at 14-bit cut)
#define RBLK     128           // rank blocks = NS/64

#define OLDK     16            // k_nms old-kept gather batch

// ws layout (bytes). part1 (u16[128][16384] = 4 MiB) ALIASES the mask buffer:
// it is dead after k_cut14, and k_iou (which writes mask) runs strictly later.
#define OFF_KEYS   0x000000u   // u32[1e6] = 4 MiB
#define OFF_CTRL   0x410000u   // [0]=count [1]=T14
#define OFF_CAND   0x410100u   // u64[NS] 64 KiB
#define OFF_BOXES  0x421000u   // float4[6016]
#define OFF_VALID  0x439000u   // u32[6016]
#define OFF_MASK   0x440000u   // u64[6016*94] = 4.52 MiB
#define OFF_PART   OFF_MASK    // u32[HB*8192] = 4 MiB (u16-packed bins)

__device__ __forceinline__ float ref_exp(float v) {
  return (float)exp((double)v);   // correctly-rounded f32 exp via double
}

__device__ __forceinline__ void decode_box(float ax, float ay, float az, float aw,
                                           float dx, float dy, float dz, float dw,
                                           float& x1, float& y1, float& x2, float& y2,
                                           bool& valid) {
  // bit-exact replica of reference fp32 op order (no FMA contraction)
  float wa = __fsub_rn(az, ax);
  float ha = __fsub_rn(aw, ay);
  float xa = __fadd_rn(ax, __fmul_rn(0.5f, wa));
  float ya = __fadd_rn(ay, __fmul_rn(0.5f, ha));
  float x  = __fadd_rn(__fmul_rn(dx, wa), xa);
  float y  = __fadd_rn(__fmul_rn(dy, ha), ya);
  float w  = __fmul_rn(ref_exp(dz), wa);
  float h  = __fmul_rn(ref_exp(dw), ha);
  float hw = __fmul_rn(0.5f, w);
  float hh = __fmul_rn(0.5f, h);
  x1 = fminf(fmaxf(__fsub_rn(x, hw), 0.0f), W_IMG - 1.0f);
  y1 = fminf(fmaxf(__fsub_rn(y, hh), 0.0f), H_IMG - 1.0f);
  x2 = fminf(fmaxf(__fadd_rn(x, hw), 0.0f), W_IMG - 1.0f);
  y2 = fminf(fmaxf(__fadd_rn(y, hh), 0.0f), H_IMG - 1.0f);
  valid = (__fsub_rn(x2, x1) >= 16.0f) && (__fsub_rn(y2, y1) >= 16.0f);
}

// wave-uniform 64-bit broadcast via v_readlane
__device__ __forceinline__ uint64_t bcast64(uint64_t v, int lane) {
  uint32_t lo = (uint32_t)__builtin_amdgcn_readlane((int)(uint32_t)v, lane);
  uint32_t hi = (uint32_t)__builtin_amdgcn_readlane((int)(uint32_t)(v >> 32), lane);
  return ((uint64_t)hi << 32) | lo;
}

__device__ __forceinline__ uint64_t shflxor64(uint64_t v, int m) {
  uint32_t lo = (uint32_t)__shfl_xor((int)(uint32_t)v, m, 64);
  uint32_t hi = (uint32_t)__shfl_xor((int)(uint32_t)(v >> 32), m, 64);
  return ((uint64_t)hi << 32) | lo;
}

// ---- K0: fused decode + logit-bit key + 14-bit LDS hist -> u16 store flush ----
// NO global atomics (round-11 lesson: 1M device-scope atomics RMW at memory
// side on non-coherent-L2 MI355X => ~250us + 25MB write storm). Each block
// builds a 16K-bin LDS hist (LDS atomics, ~8K/block) and flushes it as plain
// coalesced stores into its own u16 partial row.
__global__ void __launch_bounds__(1024) k_score(const float4* __restrict__ anchors,
                                                const float4* __restrict__ deltas,
                                                const float*  __restrict__ logits,
                                                uint32_t* __restrict__ keys,
                                                uint32_t* __restrict__ part1) {
  __shared__ uint32_t lh[NBIN];            // 64 KiB
  int tid = threadIdx.x, lane = tid & 63;
  for (int b = tid; b < NBIN; b += 1024) lh[b] = 0u;
  __syncthreads();
  for (int i = blockIdx.x * 1024 + tid; i < N_ANCH; i += HB * 1024) {
    float4 a = anchors[i];
    float4 d = deltas[i];
    // fast f32 decode (filter only; exact op order irrelevant under margin)
    float wa = a.z - a.x, ha = a.w - a.y;
    float xa = a.x + 0.5f * wa, ya = a.y + 0.5f * ha;
    float x = d.x * wa + xa, y = d.y * ha + ya;
    float w = __expf(d.z) * wa, h = __expf(d.w) * ha;
    float fx1 = fminf(fmaxf(x - 0.5f * w, 0.0f), W_IMG - 1.0f);
    float fx2 = fminf(fmaxf(x + 0.5f * w, 0.0f), W_IMG - 1.0f);
    float fy1 = fminf(fmaxf(y - 0.5f * h, 0.0f), H_IMG - 1.0f);
    float fy2 = fminf(fmaxf(y + 0.5f * h, 0.0f), H_IMG - 1.0f);
    float X = fx2 - fx1, Y = fy2 - fy1;
    bool valid = (X >= 16.0f) && (Y >= 16.0f);
    if (fabsf(X - 16.0f) < 0.02f || fabsf(Y - 16.0f) < 0.02f) {
      float ex1, ey1, ex2, ey2; bool vv;      // borderline: exact f64 recheck (rare)
      decode_box(a.x, a.y, a.z, a.w, d.x, d.y, d.z, d.w, ex1, ey1, ex2, ey2, vv);
      valid = vv;
    }
    uint32_t u = __float_as_uint(logits[i]);
    uint32_t o = (u & 0x80000000u) ? ~u : (u | 0x80000000u);  // ascending in logit
    uint32_t kd = valid ? ~o : 0xFFFFFFFFu;                   // ascending key = descending logit
    keys[i] = kd;
    uint64_t invb = __ballot(!valid);
    if (valid) {
      atomicAdd(&lh[kd >> 18], 1u);                           // LDS atomic
    } else if ((invb & ((1ull << lane) - 1ull)) == 0ull) {
      atomicAdd(&lh[NBIN - 1], (uint32_t)__popcll((unsigned long long)invb));
    }
  }
  __syncthreads();
  // flush: thread t owns bins [16t,16t+16) -> 8 packed-u16 coalesced-ish stores
  uint32_t* row = part1 + (size_t)blockIdx.x * (NBIN / 2);
  #pragma unroll
  for (int j = 0; j < 8; j++) {
    uint32_t lo = lh[16 * tid + 2 * j];
    uint32_t hi = lh[16 * tid + 2 * j + 1];
    row[8 * tid + j] = (lo & 0xFFFFu) | (hi << 16);           // counts <= 7813 fit u16
  }
}

// ---- K1: single cut over 16K bins, ONE block. Writes ctrl[1]=T14. ----
// Thread t owns bins [16t,16t+16); sums 128 u16 partials per bin, then a
// 1024-wide block scan locates the bin where cumulative >= PRE_K.
__global__ void __launch_bounds__(1024) k_cut14(const uint32_t* __restrict__ part1,
                                                uint32_t* __restrict__ ctrl) {
  __shared__ uint32_t part[1024];
  int t = threadIdx.x;
  uint32_t acc[16];
  #pragma unroll
  for (int j = 0; j < 16; j++) acc[j] = 0u;
  for (int b = 0; b < HB; b++) {
    const uint32_t* row = part1 + (size_t)b * (NBIN / 2) + 8 * t;
    #pragma unroll
    for (int j = 0; j < 8; j++) {
      uint32_t w = row[j];
      acc[2 * j]     += w & 0xFFFFu;
      acc[2 * j + 1] += w >> 16;
    }
  }
  uint32_t tot = 0;
  #pragma unroll
  for (int j = 0; j < 16; j++) tot += acc[j];
  part[t] = tot;
  __syncthreads();
  uint32_t inc = tot;
  for (int off = 1; off < 1024; off <<= 1) {
    uint32_t u = (t >= off) ? part[t - off] : 0u;
    __syncthreads();
    inc += u;
    part[t] = inc;
    __syncthreads();
  }
  uint32_t ex = inc - tot;
  if (ex < PRE_K && inc >= PRE_K) {          // exactly one thread wins
    uint32_t run = ex;
    for (int j = 0; j < 16; j++) {
      if (run + acc[j] >= PRE_K) { ctrl[1] = (uint32_t)(16 * t + j); break; }
      run += acc[j];
    }
  }
  if (t == 1023 && inc < PRE_K) ctrl[1] = NBIN - 1;   // take-everything fallback
}

// ---- K2: compact candidates (key prefix <= T14) + exact-sigmoid re-key ----
// Block-aggregated: ONE global atomic per block (977 total). cand order
// nondeterministic; fine, k_rank ranks by VALUE. ctrl non-restrict.
__global__ void __launch_bounds__(256) k_compact(const uint4* __restrict__ keys4,
                                                 const float* __restrict__ logits,
                                                 uint32_t* ctrl,
                                                 uint64_t* __restrict__ cand) {
  __shared__ uint32_t wcnt[4];
  __shared__ uint32_t bbase_s;
  int tid = threadIdx.x, lane = tid & 63, wv = tid >> 6;
  uint32_t T = ctrl[1];
  int i4 = blockIdx.x * 256 + tid;
  uint4 kk = make_uint4(~0u, ~0u, ~0u, ~0u);
  if (i4 < N4) kk = keys4[i4];
  uint32_t ks[4] = { kk.x, kk.y, kk.z, kk.w };
  bool pass[4]; uint64_t m[4];
  uint32_t tot = 0;
  #pragma unroll
  for (int e = 0; e < 4; e++) {
    pass[e] = (i4 < N4) && ((ks[e] >> 18) <= T);
    m[e] = __ballot(pass[e]);
    tot += (uint32_t)__popcll((unsigned long long)m[e]);
  }
  if (lane == 0) wcnt[wv] = tot;
  __syncthreads();
  if (tid == 0) {
    uint32_t bt = wcnt[0] + wcnt[1] + wcnt[2] + wcnt[3];
    bbase_s = bt ? atomicAdd(&ctrl[0], bt) : 0u;
  }
  __syncthreads();
  uint32_t wb = bbase_s;
  for (int w2 = 0; w2 < wv; w2++) wb += wcnt[w2];      // wave offset in block
  uint64_t lmask = (1ull << lane) - 1ull;
  #pragma unroll
  for (int e = 0; e < 4; e++) {
    if (pass[e]) {
      int i = 4 * i4 + e;
      uint32_t skey;
      if (ks[e] == 0xFFFFFFFFu) {
        skey = 0xFF800000u;                       // invalid -> -inf key
      } else {
        double xd = (double)logits[i];
        float s = (float)(1.0 / (1.0 + exp(-xd)));
        skey = 0x7FFFFFFFu & ~__float_as_uint(s); // descending-score -> ascending key
      }
      uint32_t p = wb + (uint32_t)__popcll((unsigned long long)(m[e] & lmask));
      if (p < NS) cand[p] = ((uint64_t)skey << 20) | (uint32_t)i;  // 52-bit packed
    }
    wb += (uint32_t)__popcll((unsigned long long)m[e]);
  }
}

// ---- K3: rank-by-count + gather/decode ----
// key64 all DISTINCT (idx embedded) -> rank is a bijection onto [0,M) equal to
// reference order (score desc, idx asc). 128 blocks x 4 waves.
__global__ void __launch_bounds__(256) k_rank(
    const uint32_t* __restrict__ ctrl,
    const uint64_t* __restrict__ cand,
    const float4* __restrict__ anchors,
    const float4* __restrict__ deltas,
    float4* __restrict__ boxes,
    uint32_t* __restrict__ valid) {
  __shared__ uint32_t part[4][64];
  int tid = threadIdx.x;
  int wv = tid >> 6, lane = tid & 63;
  int i = blockIdx.x * 64 + lane;            // own candidate slot (same for all 4 waves)
  uint32_t M = ctrl[0]; if (M > NS) M = NS;
  uint64_t myk = (i < (int)M) ? cand[i] : ~0ull;
  uint32_t cnt = 0;
  const int QUART = NS / 4;                  // 2048
  int jbase = wv * QUART;
  for (int s = 0; s < QUART / 64; s++) {     // 32 coalesced strips
    int j = jbase + s * 64 + lane;
    uint64_t c = (j < (int)M) ? cand[j] : ~0ull;   // sentinel: contributes 0
    #pragma unroll
    for (int s2 = 0; s2 < 64; s2++) {
      uint64_t kb = bcast64(c, s2);
      cnt += (kb < myk) ? 1u : 0u;
    }
  }
  part[wv][lane] = cnt;
  __syncthreads();
  if (wv != 0) return;
  uint32_t rank = part[0][lane] + part[1][lane] + part[2][lane] + part[3][lane];
  if (i < (int)M && rank < PRE_K) {
    uint32_t skey = (uint32_t)(myk >> 20);
    uint32_t idx  = (uint32_t)(myk & 0xFFFFFu);
    if (skey >= 0xFF800000u) {               // invalid candidate (take-everything case)
      boxes[rank] = make_float4(0.f, 0.f, 0.f, 0.f);
      valid[rank] = 0u;
    } else {
      float4 a = anchors[idx];
      float4 d = deltas[idx];
      float x1, y1, x2, y2; bool vv;
      decode_box(a.x, a.y, a.z, a.w, d.x, d.y, d.z, d.w, x1, y1, x2, y2, vv);
      boxes[rank] = make_float4(x1, y1, x2, y2);
      valid[rank] = 1u;
    }
  }
  // zero-fill all slots never touched by a rank-writer (bijection => no race)
  if ((i >= (int)M || i >= PRE_K) && i < ROWS) {
    boxes[i] = make_float4(0.f, 0.f, 0.f, 0.f);
    valid[i] = 0u;
  }
}

// ---- K4: IoU bitmask matrix, row-major mask[row*WORDS + w] ----
__global__ void __launch_bounds__(64) k_iou(const float4* __restrict__ boxes,
                                            uint64_t* __restrict__ mask) {
  int by = blockIdx.y, bx = blockIdx.x;
  if (bx < by) return;               // only words w >= row's group are ever read
  __shared__ float4 cb[64];
  int t = threadIdx.x;
  cb[t] = boxes[bx * 64 + t];
  __syncthreads();
  int i = by * 64 + t;
  float4 b = boxes[i];
  float ax1 = b.x, ay1 = b.y, ax2 = b.z, ay2 = b.w;
  float areaA = __fmul_rn(__fsub_rn(ax2, ax1), __fsub_rn(ay2, ay1));
  uint64_t bits = 0;
  for (int c = 0; c < 64; c++) {
    float4 o = cb[c];
    float areaB = __fmul_rn(__fsub_rn(o.z, o.x), __fsub_rn(o.w, o.y));
    float ix1 = fmaxf(ax1, o.x), iy1 = fmaxf(ay1, o.y);
    float ix2 = fminf(ax2, o.z), iy2 = fminf(ay2, o.w);
    float iw = fmaxf(__fsub_rn(ix2, ix1), 0.0f);
    float ih = fmaxf(__fsub_rn(iy2, iy1), 0.0f);
    float inter = __fmul_rn(iw, ih);
    float uni = __fsub_rn(__fadd_rn(areaA, areaB), inter);
    bool sup = (uni > 0.0f) && (__fdiv_rn(inter, uni) > 0.7f);
    bits |= ((uint64_t)sup) << c;
  }
  mask[(size_t)i * WORDS + bx] = bits;
}

// ---- K5: sequential NMS scan — single wave, LAZY column gather (anchor) ----
__global__ void __launch_bounds__(64, 1) k_nms(const uint64_t* __restrict__ mask,
                                               const float4* __restrict__ boxes,
                                               const uint32_t* __restrict__ valid,
                                               float* __restrict__ out) {
  __shared__ uint32_t list[1088];     // kept rows in scan order (cnt < 1064)
  int lane = threadIdx.x;
  uint64_t lmask = (1ull << lane) - 1ull;
  int cnt = 0;
  uint64_t colv = mask[(size_t)lane * WORDS + 0];   // group-0 diagonal
  uint32_t vf = valid[lane];
  uint64_t cur = 0;                                 // removed[0] = 0
  for (int g = 0; g < WORDS; g++) {
    int base = g * 64;
    bool haveNext = (g + 1 < WORDS);
    // ---- issue gathers for removed[g+1] + next diag/valid (hidden under chain) ----
    uint64_t newv = 0, colv_n = 0, oldv[OLDK];
    uint32_t vf_n = 0, om = 0;
    if (haveNext) {
      newv   = mask[(size_t)(base + lane) * WORDS + (g + 1)];        // own row's col g+1
      colv_n = mask[(size_t)(base + 64 + lane) * WORDS + (g + 1)];   // next diag
      vf_n   = valid[base + 64 + lane];
      #pragma unroll
      for (int k = 0; k < OLDK; k++) {            // previously-kept rows' col g+1
        int t = 64 * k + lane;
        uint32_t row = (t < cnt) ? list[t] : 0u;  // clamped safe address
        om |= (t < cnt) ? (1u << k) : 0u;
        oldv[k] = mask[(size_t)row * WORDS + (g + 1)];
      }
    }
    // ---- branch-free 64-step decision chain (wave-uniform SALU) ----
    uint64_t vmask = __ballot(vf != 0u);
    uint64_t alive = vmask & ~cur;
    uint64_t kept = 0;
    #pragma unroll
    for (int r = 0; r < 64; r++) {
      uint64_t mr = bcast64(colv, r);
      uint64_t take = (alive >> r) & 1ull;
      kept |= take << r;
      alive &= ~(take ? mr : 0ull);
    }
    // ---- record kept rows (in-wave, no barrier) ----
    uint32_t below = (uint32_t)__popcll((unsigned long long)(kept & lmask));
    if ((kept >> lane) & 1ull) {
      uint32_t pos = (uint32_t)cnt + below;
      if (pos < 1088u) list[pos] = (uint32_t)(base + lane);
    }
    cnt += (int)__popcll((unsigned long long)kept);
    if (cnt >= POST_K || !haveNext) break;
    // ---- pin gather batch in VGPRs (defeat load sinking), then select-OR ----
    asm volatile("" : "+v"(newv),
                      "+v"(oldv[0]),  "+v"(oldv[1]),  "+v"(oldv[2]),  "+v"(oldv[3]),
                      "+v"(oldv[4]),  "+v"(oldv[5]),  "+v"(oldv[6]),  "+v"(oldv[7]),
                      "+v"(oldv[8]),  "+v"(oldv[9]),  "+v"(oldv[10]), "+v"(oldv[11]),
                      "+v"(oldv[12]), "+v"(oldv[13]), "+v"(oldv[14]), "+v"(oldv[15]));
    uint64_t acc = ((kept >> lane) & 1ull) ? newv : 0ull;
    #pragma unroll
    for (int k = 0; k < OLDK; k++)
      acc |= oldv[k] & (0ull - (uint64_t)((om >> k) & 1u));
    #pragma unroll
    for (int off = 1; off < 64; off <<= 1)        // wave-OR reduce
      acc |= shflxor64(acc, off);
    cur = bcast64(acc, 0);                        // wave-uniform removed[g+1]
    colv = colv_n; vf = vf_n;
  }
  __syncthreads();
  float4* outv = (float4*)out;
  for (int k = lane; k < POST_K; k += 64)
    outv[k] = (k < cnt) ? boxes[list[k]] : make_float4(0.f, 0.f, 0.f, 0.f);
}

extern "C" void kernel_launch(void* const* d_in, const int* in_sizes, int n_in,
                              void* d_out, int out_size, void* d_ws, size_t ws_size,
                              hipStream_t stream) {
  const float4* anchors = (const float4*)d_in[1];
  const float4* deltas  = (const float4*)d_in[2];
  const float*  logits  = (const float*)d_in[3];
  char* w = (char*)d_ws;
  uint32_t* keys  = (uint32_t*)(w + OFF_KEYS);
  uint32_t* part1 = (uint32_t*)(w + OFF_PART);   // aliases mask[0..4MiB)
  uint32_t* ctrl  = (uint32_t*)(w + OFF_CTRL);
  uint64_t* cand  = (uint64_t*)(w + OFF_CAND);
  float4*   boxes = (float4*)(w + OFF_BOXES);
  uint32_t* valid = (uint32_t*)(w + OFF_VALID);
  uint64_t* mask  = (uint64_t*)(w + OFF_MASK);
  float*    out   = (float*)d_out;

  hipMemsetAsync(w + OFF_CTRL, 0, 256, stream);  // counters only (part1 fully overwritten)

  k_score<<<HB, 1024, 0, stream>>>(anchors, deltas, logits, keys, part1);
  k_cut14<<<1, 1024, 0, stream>>>(part1, ctrl);
  k_compact<<<NBLK256, 256, 0, stream>>>((const uint4*)keys, logits, ctrl, cand);
  k_rank<<<RBLK, 256, 0, stream>>>(ctrl, cand, anchors, deltas, boxes, valid);
  k_iou<<<dim3(WORDS, WORDS), 64, 0, stream>>>(boxes, mask);
  k_nms<<<1, 64, 0, stream>>>(mask, boxes, valid, out);
}

// Round 13
// 225.227 us; speedup vs baseline: 2.1978x; 1.1758x over previous
//
#include <hip/hip_runtime.h>
#include <stdint.h>
#include <math.h>

#define N_ANCH   1000000
#define N4       (N_ANCH / 4)          // 250000 uint4 key packs
#define NBLK256  ((N4 + 255) / 256)    // 977 blocks (k_compact)
#define PRE_K    6000
#define POST_K   1000
#define WORDS    94            // ceil(6000/64) -> 6016 bit columns
#define ROWS     6016          // WORDS*64
#define W_IMG    1333.0f
#define H_IMG    800.0f

#define HB       245           // k_score blocks (1024 thr, 4 anchors/thread)
#define NBIN     8192          // 13-bit histogram (32 KiB LDS / 32 KiB global)
#define KSHIFT   19            // key >> 19 = 13-bit prefix
#define NS       8192          // candidate cap; cut-bin <= ~1900 < NS-PRE_K=2192
#define RBLK     128           // rank blocks = NS/64

#define OLDK     16            // k_nms old-kept gather batch

// ws layout (bytes)
#define OFF_KEYS   0x000000u   // u32[1e6] = 4 MiB
#define OFF_CTRL   0x400000u   // [0]=count [1]=T13
#define OFF_HIST   0x400100u   // u32[8192] = 32 KiB (memset with ctrl, one call)
#define OFF_CAND   0x410000u   // u64[NS] = 64 KiB
#define OFF_BOXES  0x420000u   // float4[6016] = 94 KiB
#define OFF_VALID  0x438000u   // u32[6016]
#define OFF_MASK   0x440000u   // u64[6016*94] = 4.52 MiB

__device__ __forceinline__ float ref_exp(float v) {
  return (float)exp((double)v);   // correctly-rounded f32 exp via double
}

__device__ __forceinline__ void decode_box(float ax, float ay, float az, float aw,
                                           float dx, float dy, float dz, float dw,
                                           float& x1, float& y1, float& x2, float& y2,
                                           bool& valid) {
  // bit-exact replica of reference fp32 op order (no FMA contraction)
  float wa = __fsub_rn(az, ax);
  float ha = __fsub_rn(aw, ay);
  float xa = __fadd_rn(ax, __fmul_rn(0.5f, wa));
  float ya = __fadd_rn(ay, __fmul_rn(0.5f, ha));
  float x  = __fadd_rn(__fmul_rn(dx, wa), xa);
  float y  = __fadd_rn(__fmul_rn(dy, ha), ya);
  float w  = __fmul_rn(ref_exp(dz), wa);
  float h  = __fmul_rn(ref_exp(dw), ha);
  float hw = __fmul_rn(0.5f, w);
  float hh = __fmul_rn(0.5f, h);
  x1 = fminf(fmaxf(__fsub_rn(x, hw), 0.0f), W_IMG - 1.0f);
  y1 = fminf(fmaxf(__fsub_rn(y, hh), 0.0f), H_IMG - 1.0f);
  x2 = fminf(fmaxf(__fadd_rn(x, hw), 0.0f), W_IMG - 1.0f);
  y2 = fminf(fmaxf(__fadd_rn(y, hh), 0.0f), H_IMG - 1.0f);
  valid = (__fsub_rn(x2, x1) >= 16.0f) && (__fsub_rn(y2, y1) >= 16.0f);
}

// wave-uniform 64-bit broadcast via v_readlane
__device__ __forceinline__ uint64_t bcast64(uint64_t v, int lane) {
  uint32_t lo = (uint32_t)__builtin_amdgcn_readlane((int)(uint32_t)v, lane);
  uint32_t hi = (uint32_t)__builtin_amdgcn_readlane((int)(uint32_t)(v >> 32), lane);
  return ((uint64_t)hi << 32) | lo;
}

__device__ __forceinline__ uint64_t shflxor64(uint64_t v, int m) {
  uint32_t lo = (uint32_t)__shfl_xor((int)(uint32_t)v, m, 64);
  uint32_t hi = (uint32_t)__shfl_xor((int)(uint32_t)(v >> 32), m, 64);
  return ((uint64_t)hi << 32) | lo;
}

// ---- K0: fused decode + logit-bit key + 13-bit LDS hist + sparse atomic flush ----
// Round-12 lessons fixed: 245 blocks x 1024 (2 blocks/CU, full machine, 32KB
// LDS); flush is sparse atomics to a 32KB global hist (round-8-proven regime:
// ~800K atomics to a SMALL footprint is fine; 1M to 256KB was the round-11
// disaster). Fusing deletes the separate decode launch + one 4MB key re-read.
__global__ void __launch_bounds__(1024) k_score(const float4* __restrict__ anchors,
                                                const float4* __restrict__ deltas,
                                                const float*  __restrict__ logits,
                                                uint32_t* __restrict__ keys,
                                                uint32_t* __restrict__ hist) {
  __shared__ uint32_t lh[NBIN];            // 32 KiB
  int tid = threadIdx.x, lane = tid & 63;
  for (int b = tid; b < NBIN; b += 1024) lh[b] = 0u;
  __syncthreads();
  for (int i = blockIdx.x * 1024 + tid; i < N_ANCH; i += HB * 1024) {
    float4 a = anchors[i];
    float4 d = deltas[i];
    // fast f32 decode (filter only; exact op order irrelevant under margin)
    float wa = a.z - a.x, ha = a.w - a.y;
    float xa = a.x + 0.5f * wa, ya = a.y + 0.5f * ha;
    float x = d.x * wa + xa, y = d.y * ha + ya;
    float w = __expf(d.z) * wa, h = __expf(d.w) * ha;
    float fx1 = fminf(fmaxf(x - 0.5f * w, 0.0f), W_IMG - 1.0f);
    float fx2 = fminf(fmaxf(x + 0.5f * w, 0.0f), W_IMG - 1.0f);
    float fy1 = fminf(fmaxf(y - 0.5f * h, 0.0f), H_IMG - 1.0f);
    float fy2 = fminf(fmaxf(y + 0.5f * h, 0.0f), H_IMG - 1.0f);
    float X = fx2 - fx1, Y = fy2 - fy1;
    bool valid = (X >= 16.0f) && (Y >= 16.0f);
    if (fabsf(X - 16.0f) < 0.02f || fabsf(Y - 16.0f) < 0.02f) {
      float ex1, ey1, ex2, ey2; bool vv;      // borderline: exact f64 recheck (rare)
      decode_box(a.x, a.y, a.z, a.w, d.x, d.y, d.z, d.w, ex1, ey1, ex2, ey2, vv);
      valid = vv;
    }
    uint32_t u = __float_as_uint(logits[i]);
    uint32_t o = (u & 0x80000000u) ? ~u : (u | 0x80000000u);  // ascending in logit
    uint32_t kd = valid ? ~o : 0xFFFFFFFFu;                   // ascending key = descending logit
    keys[i] = kd;
    // valid keys never map to bin 8191 (would require NaN logit) -> bin 8191 is pure-invalid
    uint64_t invb = __ballot(!valid);
    if (valid) {
      atomicAdd(&lh[kd >> KSHIFT], 1u);                       // LDS atomic
    } else if ((invb & ((1ull << lane) - 1ull)) == 0ull) {
      atomicAdd(&lh[NBIN - 1], (uint32_t)__popcll((unsigned long long)invb));
    }
  }
  __syncthreads();
  for (int b = tid; b < NBIN; b += 1024) {     // sparse flush: small-footprint atomics
    uint32_t cv = lh[b];
    if (cv) atomicAdd(&hist[b], cv);
  }
}

// ---- K1: single cut over 8192 bins, ONE block reading 32 KB. ctrl[1]=T13. ----
__global__ void __launch_bounds__(1024) k_cut13(const uint32_t* __restrict__ hist,
                                                uint32_t* __restrict__ ctrl) {
  __shared__ uint32_t part[1024];
  int t = threadIdx.x;
  const uint4* h4 = (const uint4*)hist;
  uint4 q0 = h4[2 * t], q1 = h4[2 * t + 1];   // bins [8t, 8t+8)
  uint32_t b[8] = { q0.x, q0.y, q0.z, q0.w, q1.x, q1.y, q1.z, q1.w };
  uint32_t tot = 0;
  #pragma unroll
  for (int j = 0; j < 8; j++) tot += b[j];
  part[t] = tot;
  __syncthreads();
  uint32_t inc = tot;
  for (int off = 1; off < 1024; off <<= 1) {
    uint32_t u = (t >= off) ? part[t - off] : 0u;
    __syncthreads();
    inc += u;
    part[t] = inc;
    __syncthreads();
  }
  uint32_t ex = inc - tot;
  if (ex < PRE_K && inc >= PRE_K) {            // exactly one thread wins
    uint32_t run = ex;
    for (int j = 0; j < 8; j++) {
      if (run + b[j] >= PRE_K) { ctrl[1] = (uint32_t)(8 * t + j); break; }
      run += b[j];
    }
  }
  if (t == 1023 && inc < PRE_K) ctrl[1] = NBIN - 1;   // take-everything fallback
}

// ---- K2: compact candidates (key prefix <= T13) + exact-sigmoid re-key ----
// Block-aggregated: ONE global atomic per block (977 total). cand order
// nondeterministic; fine, k_rank ranks by VALUE. ctrl non-restrict.
__global__ void __launch_bounds__(256) k_compact(const uint4* __restrict__ keys4,
                                                 const float* __restrict__ logits,
                                                 uint32_t* ctrl,
                                                 uint64_t* __restrict__ cand) {
  __shared__ uint32_t wcnt[4];
  __shared__ uint32_t bbase_s;
  int tid = threadIdx.x, lane = tid & 63, wv = tid >> 6;
  uint32_t T = ctrl[1];
  int i4 = blockIdx.x * 256 + tid;
  uint4 kk = make_uint4(~0u, ~0u, ~0u, ~0u);
  if (i4 < N4) kk = keys4[i4];
  uint32_t ks[4] = { kk.x, kk.y, kk.z, kk.w };
  bool pass[4]; uint64_t m[4];
  uint32_t tot = 0;
  #pragma unroll
  for (int e = 0; e < 4; e++) {
    pass[e] = (i4 < N4) && ((ks[e] >> KSHIFT) <= T);
    m[e] = __ballot(pass[e]);
    tot += (uint32_t)__popcll((unsigned long long)m[e]);
  }
  if (lane == 0) wcnt[wv] = tot;
  __syncthreads();
  if (tid == 0) {
    uint32_t bt = wcnt[0] + wcnt[1] + wcnt[2] + wcnt[3];
    bbase_s = bt ? atomicAdd(&ctrl[0], bt) : 0u;
  }
  __syncthreads();
  uint32_t wb = bbase_s;
  for (int w2 = 0; w2 < wv; w2++) wb += wcnt[w2];      // wave offset in block
  uint64_t lmask = (1ull << lane) - 1ull;
  #pragma unroll
  for (int e = 0; e < 4; e++) {
    if (pass[e]) {
      int i = 4 * i4 + e;
      uint32_t skey;
      if (ks[e] == 0xFFFFFFFFu) {
        skey = 0xFF800000u;                       // invalid -> -inf key
      } else {
        double xd = (double)logits[i];
        float s = (float)(1.0 / (1.0 + exp(-xd)));
        skey = 0x7FFFFFFFu & ~__float_as_uint(s); // descending-score -> ascending key
      }
      uint32_t p = wb + (uint32_t)__popcll((unsigned long long)(m[e] & lmask));
      if (p < NS) cand[p] = ((uint64_t)skey << 20) | (uint32_t)i;  // 52-bit packed
    }
    wb += (uint32_t)__popcll((unsigned long long)m[e]);
  }
}

// ---- K3: rank-by-count + gather/decode ----
// key64 all DISTINCT (idx embedded) -> rank is a bijection onto [0,M) equal to
// reference order (score desc, idx asc). 128 blocks x 4 waves.
__global__ void __launch_bounds__(256) k_rank(
    const uint32_t* __restrict__ ctrl,
    const uint64_t* __restrict__ cand,
    const float4* __restrict__ anchors,
    const float4* __restrict__ deltas,
    float4* __restrict__ boxes,
    uint32_t* __restrict__ valid) {
  __shared__ uint32_t part[4][64];
  int tid = threadIdx.x;
  int wv = tid >> 6, lane = tid & 63;
  int i = blockIdx.x * 64 + lane;            // own candidate slot (same for all 4 waves)
  uint32_t M = ctrl[0]; if (M > NS) M = NS;
  uint64_t myk = (i < (int)M) ? cand[i] : ~0ull;
  uint32_t cnt = 0;
  const int QUART = NS / 4;                  // 2048
  int jbase = wv * QUART;
  for (int s = 0; s < QUART / 64; s++) {     // 32 coalesced strips
    int j = jbase + s * 64 + lane;
    uint64_t c = (j < (int)M) ? cand[j] : ~0ull;   // sentinel: contributes 0
    #pragma unroll
    for (int s2 = 0; s2 < 64; s2++) {
      uint64_t kb = bcast64(c, s2);
      cnt += (kb < myk) ? 1u : 0u;
    }
  }
  part[wv][lane] = cnt;
  __syncthreads();
  if (wv != 0) return;
  uint32_t rank = part[0][lane] + part[1][lane] + part[2][lane] + part[3][lane];
  if (i < (int)M && rank < PRE_K) {
    uint32_t skey = (uint32_t)(myk >> 20);
    uint32_t idx  = (uint32_t)(myk & 0xFFFFFu);
    if (skey >= 0xFF800000u) {               // invalid candidate (take-everything case)
      boxes[rank] = make_float4(0.f, 0.f, 0.f, 0.f);
      valid[rank] = 0u;
    } else {
      float4 a = anchors[idx];
      float4 d = deltas[idx];
      float x1, y1, x2, y2; bool vv;
      decode_box(a.x, a.y, a.z, a.w, d.x, d.y, d.z, d.w, x1, y1, x2, y2, vv);
      boxes[rank] = make_float4(x1, y1, x2, y2);
      valid[rank] = 1u;
    }
  }
  // zero-fill all slots never touched by a rank-writer (bijection => no race)
  if ((i >= (int)M || i >= PRE_K) && i < ROWS) {
    boxes[i] = make_float4(0.f, 0.f, 0.f, 0.f);
    valid[i] = 0u;
  }
}

// ---- K4: IoU bitmask matrix, row-major mask[row*WORDS + w] ----
__global__ void __launch_bounds__(64) k_iou(const float4* __restrict__ boxes,
                                            uint64_t* __restrict__ mask) {
  int by = blockIdx.y, bx = blockIdx.x;
  if (bx < by) return;               // only words w >= row's group are ever read
  __shared__ float4 cb[64];
  int t = threadIdx.x;
  cb[t] = boxes[bx * 64 + t];
  __syncthreads();
  int i = by * 64 + t;
  float4 b = boxes[i];
  float ax1 = b.x, ay1 = b.y, ax2 = b.z, ay2 = b.w;
  float areaA = __fmul_rn(__fsub_rn(ax2, ax1), __fsub_rn(ay2, ay1));
  uint64_t bits = 0;
  for (int c = 0; c < 64; c++) {
    float4 o = cb[c];
    float areaB = __fmul_rn(__fsub_rn(o.z, o.x), __fsub_rn(o.w, o.y));
    float ix1 = fmaxf(ax1, o.x), iy1 = fmaxf(ay1, o.y);
    float ix2 = fminf(ax2, o.z), iy2 = fminf(ay2, o.w);
    float iw = fmaxf(__fsub_rn(ix2, ix1), 0.0f);
    float ih = fmaxf(__fsub_rn(iy2, iy1), 0.0f);
    float inter = __fmul_rn(iw, ih);
    float uni = __fsub_rn(__fadd_rn(areaA, areaB), inter);
    bool sup = (uni > 0.0f) && (__fdiv_rn(inter, uni) > 0.7f);
    bits |= ((uint64_t)sup) << c;
  }
  mask[(size_t)i * WORDS + bx] = bits;
}

// ---- K5: sequential NMS scan — single wave, LAZY column gather (anchor) ----
__global__ void __launch_bounds__(64, 1) k_nms(const uint64_t* __restrict__ mask,
                                               const float4* __restrict__ boxes,
                                               const uint32_t* __restrict__ valid,
                                               float* __restrict__ out) {
  __shared__ uint32_t list[1088];     // kept rows in scan order (cnt < 1064)
  int lane = threadIdx.x;
  uint64_t lmask = (1ull << lane) - 1ull;
  int cnt = 0;
  uint64_t colv = mask[(size_t)lane * WORDS + 0];   // group-0 diagonal
  uint32_t vf = valid[lane];
  uint64_t cur = 0;                                 // removed[0] = 0
  for (int g = 0; g < WORDS; g++) {
    int base = g * 64;
    bool haveNext = (g + 1 < WORDS);
    // ---- issue gathers for removed[g+1] + next diag/valid (hidden under chain) ----
    uint64_t newv = 0, colv_n = 0, oldv[OLDK];
    uint32_t vf_n = 0, om = 0;
    if (haveNext) {
      newv   = mask[(size_t)(base + lane) * WORDS + (g + 1)];        // own row's col g+1
      colv_n = mask[(size_t)(base + 64 + lane) * WORDS + (g + 1)];   // next diag
      vf_n   = valid[base + 64 + lane];
      #pragma unroll
      for (int k = 0; k < OLDK; k++) {            // previously-kept rows' col g+1
        int t = 64 * k + lane;
        uint32_t row = (t < cnt) ? list[t] : 0u;  // clamped safe address
        om |= (t < cnt) ? (1u << k) : 0u;
        oldv[k] = mask[(size_t)row * WORDS + (g + 1)];
      }
    }
    // ---- branch-free 64-step decision chain (wave-uniform SALU) ----
    uint64_t vmask = __ballot(vf != 0u);
    uint64_t alive = vmask & ~cur;
    uint64_t kept = 0;
    #pragma unroll
    for (int r = 0; r < 64; r++) {
      uint64_t mr = bcast64(colv, r);
      uint64_t take = (alive >> r) & 1ull;
      kept |= take << r;
      alive &= ~(take ? mr : 0ull);
    }
    // ---- record kept rows (in-wave, no barrier) ----
    uint32_t below = (uint32_t)__popcll((unsigned long long)(kept & lmask));
    if ((kept >> lane) & 1ull) {
      uint32_t pos = (uint32_t)cnt + below;
      if (pos < 1088u) list[pos] = (uint32_t)(base + lane);
    }
    cnt += (int)__popcll((unsigned long long)kept);
    if (cnt >= POST_K || !haveNext) break;
    // ---- pin gather batch in VGPRs (defeat load sinking), then select-OR ----
    asm volatile("" : "+v"(newv),
                      "+v"(oldv[0]),  "+v"(oldv[1]),  "+v"(oldv[2]),  "+v"(oldv[3]),
                      "+v"(oldv[4]),  "+v"(oldv[5]),  "+v"(oldv[6]),  "+v"(oldv[7]),
                      "+v"(oldv[8]),  "+v"(oldv[9]),  "+v"(oldv[10]), "+v"(oldv[11]),
                      "+v"(oldv[12]), "+v"(oldv[13]), "+v"(oldv[14]), "+v"(oldv[15]));
    uint64_t acc = ((kept >> lane) & 1ull) ? newv : 0ull;
    #pragma unroll
    for (int k = 0; k < OLDK; k++)
      acc |= oldv[k] & (0ull - (uint64_t)((om >> k) & 1u));
    #pragma unroll
    for (int off = 1; off < 64; off <<= 1)        // wave-OR reduce
      acc |= shflxor64(acc, off);
    cur = bcast64(acc, 0);                        // wave-uniform removed[g+1]
    colv = colv_n; vf = vf_n;
  }
  __syncthreads();
  float4* outv = (float4*)out;
  for (int k = lane; k < POST_K; k += 64)
    outv[k] = (k < cnt) ? boxes[list[k]] : make_float4(0.f, 0.f, 0.f, 0.f);
}

extern "C" void kernel_launch(void* const* d_in, const int* in_sizes, int n_in,
                              void* d_out, int out_size, void* d_ws, size_t ws_size,
                              hipStream_t stream) {
  const float4* anchors = (const float4*)d_in[1];
  const float4* deltas  = (const float4*)d_in[2];
  const float*  logits  = (const float*)d_in[3];
  char* w = (char*)d_ws;
  uint32_t* keys  = (uint32_t*)(w + OFF_KEYS);
  uint32_t* ctrl  = (uint32_t*)(w + OFF_CTRL);
  uint32_t* hist  = (uint32_t*)(w + OFF_HIST);
  uint64_t* cand  = (uint64_t*)(w + OFF_CAND);
  float4*   boxes = (float4*)(w + OFF_BOXES);
  uint32_t* valid = (uint32_t*)(w + OFF_VALID);
  uint64_t* mask  = (uint64_t*)(w + OFF_MASK);
  float*    out   = (float*)d_out;

  hipMemsetAsync(w + OFF_CTRL, 0, 0x8100, stream);  // ctrl (256B) + hist (32KB), one call

  k_score<<<HB, 1024, 0, stream>>>(anchors, deltas, logits, keys, hist);
  k_cut13<<<1, 1024, 0, stream>>>(hist, ctrl);
  k_compact<<<NBLK256, 256, 0, stream>>>((const uint4*)keys, logits, ctrl, cand);
  k_rank<<<RBLK, 256, 0, stream>>>(ctrl, cand, anchors, deltas, boxes, valid);
  k_iou<<<dim3(WORDS, WORDS), 64, 0, stream>>>(boxes, mask);
  k_nms<<<1, 64, 0, stream>>>(mask, boxes, valid, out);
}